// Round 8
// baseline (48119.559 us; speedup 1.0000x reference)
//
#include <hip/hip_runtime.h>
#include <hip/hip_bf16.h>
#include <cstdint>
#include <cstddef>

// ---------------------------------------------------------------------------
// Sentinel writer (fp32 world — codes are directly visible in readback).
// ---------------------------------------------------------------------------
__global__ void write_val(float* o, float v) {
  if (threadIdx.x == 0 && blockIdx.x == 0) o[0] = v;
}

// ---------------------------------------------------------------------------
// Textbook tiled GEMM: C[M,N] = A[M,K] * B[N,K]^T, all fp32.
// Block 256 = 16x16 C tile; K-tiles of 16 staged to LDS.
// grid = (N/16, M/16). M,N,K multiples of 16.
// ---------------------------------------------------------------------------
__global__ __launch_bounds__(256) void gemm_tile16(
    const float* __restrict__ A, const float* __restrict__ Bw,
    float* __restrict__ C, int M, int N, int K)
{
  __shared__ float lA[16][17];
  __shared__ float lB[16][17];
  const int t  = threadIdx.x;
  const int tx = t & 15, ty = t >> 4;
  const size_t m0 = (size_t)blockIdx.y * 16;
  const size_t n0 = (size_t)blockIdx.x * 16;

  float acc = 0.0f;
  for (int k0 = 0; k0 < K; k0 += 16) {
    lA[ty][tx] = A [(m0 + ty) * (size_t)K + k0 + tx];
    lB[ty][tx] = Bw[(n0 + ty) * (size_t)K + k0 + tx];
    __syncthreads();
    #pragma unroll
    for (int j = 0; j < 16; ++j) acc += lA[ty][j] * lB[tx][j];
    __syncthreads();
  }
  C[(m0 + ty) * (size_t)N + n0 + tx] = acc;
}

// ---------------------------------------------------------------------------
// Gemma RMSNorm + RoPE, in place (fp32). Block 256 per (row, head).
// hstride: head offset within a row (512 q+gate / 256 k); rowlen: row stride.
// ---------------------------------------------------------------------------
__global__ __launch_bounds__(256) void norm_rope_naive(
    float* __restrict__ data, const float* __restrict__ w,
    const float* __restrict__ ropec, int hstride, int rowlen, int s_off)
{
  __shared__ float red[256];
  __shared__ float buf[256];
  const int t = threadIdx.x;
  const int m = blockIdx.x, h = blockIdx.y;

  float* p = data + (size_t)m * rowlen + h * hstride + t;
  const float x = *p;
  red[t] = x * x;
  __syncthreads();
  for (int s = 128; s > 0; s >>= 1) {
    if (t < s) red[t] += red[t + s];
    __syncthreads();
  }
  const float rr = rsqrtf(red[0] * (1.0f / 256.0f) + 1e-6f);
  float xn = x * rr * (1.0f + w[t]);
  buf[t] = xn;
  __syncthreads();
  if (t < 64) {  // RoPE on dims 0..63: out = q*cos + rot_half(q)*sin
    const float part = buf[(t < 32) ? t + 32 : t - 32];
    const float sgn  = (t < 32) ? -1.0f : 1.0f;
    const float* rc = ropec + (size_t)(s_off + m) * 128;
    xn = xn * rc[t] + sgn * part * rc[64 + t];
  }
  *p = xn;
}

// ---------------------------------------------------------------------------
// Naive full attention (GQA rep=4) + sigmoid gate, fp32. Block per (q, head).
// qg row layout per head: [q 256 | gate 256].
// ---------------------------------------------------------------------------
__global__ __launch_bounds__(256) void attn_naive(
    const float* __restrict__ qg, const float* __restrict__ kb,
    const float* __restrict__ vb, float* __restrict__ yb)
{
  __shared__ float qs[256];
  __shared__ float sc[2048];
  __shared__ float red[256];
  const int t = threadIdx.x;
  const int m = blockIdx.x, h = blockIdx.y, kvh = h >> 2;

  const float* qrow = qg + (size_t)m * 8192 + h * 512;
  qs[t] = qrow[t];
  __syncthreads();

  // scores
  for (int kk = 0; kk < 8; ++kk) {
    const int ki = kk * 256 + t;
    const float* krow = kb + (size_t)ki * 1024 + kvh * 256;
    float s = 0.0f;
    for (int d = 0; d < 256; ++d) s += qs[d] * krow[d];
    sc[ki] = s * 0.0625f;           // 256^-0.5
  }
  __syncthreads();

  // max
  float lm = -1e30f;
  for (int kk = 0; kk < 8; ++kk) lm = fmaxf(lm, sc[kk * 256 + t]);
  red[t] = lm;
  __syncthreads();
  for (int s = 128; s > 0; s >>= 1) {
    if (t < s) red[t] = fmaxf(red[t], red[t + s]);
    __syncthreads();
  }
  const float mx = red[0];
  __syncthreads();

  // exp + sum
  float ls = 0.0f;
  for (int kk = 0; kk < 8; ++kk) {
    const int ki = kk * 256 + t;
    const float p = expf(sc[ki] - mx);
    sc[ki] = p;
    ls += p;
  }
  red[t] = ls;
  __syncthreads();
  for (int s = 128; s > 0; s >>= 1) {
    if (t < s) red[t] += red[t + s];
    __syncthreads();
  }
  const float inv = 1.0f / red[0];

  // PV
  float o = 0.0f;
  const float* vcol = vb + kvh * 256 + t;
  for (int k = 0; k < 2048; ++k) o += sc[k] * vcol[(size_t)k * 1024];

  const float gate = qrow[256 + t];
  const float sig = 1.0f / (1.0f + expf(-gate));
  yb[(size_t)m * 4096 + h * 256 + t] = o * inv * sig;
}

// ---------------------------------------------------------------------------
// Post-check: NaN anywhere in out -> sentinel 777 (out is failing anyway).
// ---------------------------------------------------------------------------
__global__ __launch_bounds__(256) void scan_out_nan(
    const float* __restrict__ o, size_t n, unsigned* __restrict__ hdr)
{
  unsigned bad = 0;
  for (size_t i = (size_t)blockIdx.x * 256 + threadIdx.x; i < n;
       i += (size_t)gridDim.x * 256) {
    const float v = o[i];
    if (!(v == v)) bad = 1;
  }
  if (__any(bad) && (threadIdx.x & 63) == 0) atomicOr(hdr, 1u);
}

__global__ void encode_verdict(float* o, const unsigned* hdr) {
  if (threadIdx.x == 0 && hdr[0]) o[0] = 777.0f;
}

// ---------------------------------------------------------------------------
extern "C" void kernel_launch(void* const* d_in, const int* in_sizes, int n_in,
                              void* d_out, int out_size, void* d_ws, size_t ws_size,
                              hipStream_t stream) {
  const float* x    = (const float*)d_in[0];
  const float* rope = (const float*)d_in[1];
  const float* wq   = (const float*)d_in[2];
  const float* wk   = (const float*)d_in[3];
  const float* wv   = (const float*)d_in[4];
  const float* wo   = (const float*)d_in[5];
  const float* qnw  = (const float*)d_in[6];
  const float* knw  = (const float*)d_in[7];
  float* out = (float*)d_out;

  // --- contract guards ---
  if (out_size != 16777216) {                       // 2*2048*4096
    write_val<<<1, 64, 0, stream>>>(out, 2000.0f);
    return;
  }
  const bool sizes_ok = (n_in == 8) &&
      in_sizes[0] == 16777216 && in_sizes[1] == 262144 &&
      in_sizes[2] == 33554432 && in_sizes[3] == 4194304 &&
      in_sizes[4] == 4194304  && in_sizes[5] == 16777216 &&
      in_sizes[6] == 256      && in_sizes[7] == 256;
  if (!sizes_ok) {
    write_val<<<1, 64, 0, stream>>>(out, 2500.0f);
    return;
  }

  // --- ws layout (fp32): [hdr 1KB | k 8.39MB | v 8.39MB | qg CH*32KB | y CH*16KB]
  const size_t KVB = 2048ull * 1024 * 4;
  const size_t fixed = 1024 + 2 * KVB;
  int CH = 2048;
  while (CH > 128 && fixed + (size_t)CH * 49152 > ws_size) CH >>= 1;
  if (fixed + (size_t)CH * 49152 > ws_size) {
    write_val<<<1, 64, 0, stream>>>(out, 3000.0f);
    return;
  }
  char* ws = (char*)d_ws;
  unsigned* hdr = (unsigned*)ws;
  float* kbb = (float*)(ws + 1024);
  float* vbb = (float*)(ws + 1024 + KVB);
  float* qgc = (float*)(ws + fixed);
  float* ycc = (float*)(ws + fixed + (size_t)CH * 32768);

  hipMemsetAsync(hdr, 0, 64, stream);

  for (int b = 0; b < 2; ++b) {
    const float* xb = x + (size_t)b * 2048 * 4096;
    gemm_tile16<<<dim3(64, 128), 256, 0, stream>>>(xb, wk, kbb, 2048, 1024, 4096);
    norm_rope_naive<<<dim3(2048, 4), 256, 0, stream>>>(kbb, knw, rope, 256, 1024, 0);
    gemm_tile16<<<dim3(64, 128), 256, 0, stream>>>(xb, wv, vbb, 2048, 1024, 4096);
    for (int c = 0; c < 2048; c += CH) {
      gemm_tile16<<<dim3(512, CH / 16), 256, 0, stream>>>(
          xb + (size_t)c * 4096, wq, qgc, CH, 8192, 4096);
      norm_rope_naive<<<dim3(CH, 16), 256, 0, stream>>>(qgc, qnw, rope, 512, 8192, c);
      attn_naive<<<dim3(CH, 16), 256, 0, stream>>>(qgc, kbb, vbb, ycc);
      gemm_tile16<<<dim3(256, CH / 16), 256, 0, stream>>>(
          ycc, wo, out + ((size_t)b * 2048 + c) * 4096, CH, 4096, 4096);
    }
  }

  // verdict channel: NaN in out -> 777
  scan_out_nan<<<1024, 256, 0, stream>>>(out, (size_t)out_size, hdr);
  encode_verdict<<<1, 64, 0, stream>>>(out, hdr);
}

// Round 9
// 3941.486 us; speedup vs baseline: 12.2085x; 12.2085x over previous
//
#include <hip/hip_runtime.h>
#include <hip/hip_bf16.h>
#include <cstdint>
#include <cstddef>

typedef __bf16 bf16;
typedef __bf16 bf16x8 __attribute__((ext_vector_type(8)));
typedef __bf16 bf16x4 __attribute__((ext_vector_type(4)));
typedef float f32x4 __attribute__((ext_vector_type(4)));

#define MFMA16(a, b, c) __builtin_amdgcn_mfma_f32_16x16x32_bf16((a), (b), (c), 0, 0, 0)

// Order + drain LDS ops (TBAA can't see bf16x4-write vs bf16x8-read aliasing).
#define LDS_FENCE() do { \
    __builtin_amdgcn_sched_barrier(0); \
    asm volatile("s_waitcnt lgkmcnt(0)" ::: "memory"); \
    __builtin_amdgcn_sched_barrier(0); \
  } while (0)

// Split fp32 -> bf16 hi + bf16 residual (hi+lo carries ~16 mantissa bits).
__device__ __forceinline__ void split8(const float* f, bf16x8& hi, bf16x8& lo) {
  #pragma unroll
  for (int j = 0; j < 8; ++j) {
    const bf16 h = (bf16)f[j];
    hi[j] = h;
    lo[j] = (bf16)(f[j] - (float)h);
  }
}

__global__ void write_val(float* o, float v) {
  if (threadIdx.x == 0 && blockIdx.x == 0) o[0] = v;
}

// ---------------------------------------------------------------------------
// Split-bf16 MFMA GEMM: C[M,N] = A[M,K]*B[N,K]^T, fp32 I/O, ~fp32 accuracy.
// 128x128 tile, BK=64, 4 waves (2x2 of 64x64). acc += Ah*Bh + Ah*Bl + Al*Bh.
// M,N mult of 128; K mult of 64. grid = (N/128, M/128).
// ---------------------------------------------------------------------------
__global__ __launch_bounds__(256) void gemm_bt_split(
    const float* __restrict__ A, const float* __restrict__ Bw,
    float* __restrict__ C, int M, int N, int K)
{
  __shared__ bf16 lAh[128 * 72], lAl[128 * 72];
  __shared__ bf16 lBh[128 * 72], lBl[128 * 72];
  const int tid  = threadIdx.x;
  const int wave = tid >> 6, lane = tid & 63;
  const int g = lane >> 4, q = lane & 15;
  const size_t m0 = (size_t)blockIdx.y * 128, n0 = (size_t)blockIdx.x * 128;
  const int wm = wave >> 1, wn = wave & 1;
  const int sc8 = (tid & 7) << 3;

  f32x4 acc[4][4] = {};

  for (int k0 = 0; k0 < K; k0 += 64) {
    float va[4][8], vb[4][8];
    #pragma unroll
    for (int i = 0; i < 4; ++i) {
      const int row = i * 32 + (tid >> 3);
      const float* pa = &A [(m0 + row) * (size_t)K + k0 + sc8];
      const float* pb = &Bw[(n0 + row) * (size_t)K + k0 + sc8];
      *(f32x4*)&va[i][0] = *(const f32x4*)pa;
      *(f32x4*)&va[i][4] = *(const f32x4*)(pa + 4);
      *(f32x4*)&vb[i][0] = *(const f32x4*)pb;
      *(f32x4*)&vb[i][4] = *(const f32x4*)(pb + 4);
    }
    __syncthreads();                      // prev-tile LDS reads done
    #pragma unroll
    for (int i = 0; i < 4; ++i) {
      const int row = i * 32 + (tid >> 3);
      bf16x8 hi, lo;
      split8(va[i], hi, lo);
      *(bf16x8*)&lAh[row * 72 + sc8] = hi;
      *(bf16x8*)&lAl[row * 72 + sc8] = lo;
      split8(vb[i], hi, lo);
      *(bf16x8*)&lBh[row * 72 + sc8] = hi;
      *(bf16x8*)&lBl[row * 72 + sc8] = lo;
    }
    __syncthreads();
    #pragma unroll
    for (int kk = 0; kk < 2; ++kk) {
      bf16x8 ah[4], al[4], bh[4], bl[4];
      #pragma unroll
      for (int f = 0; f < 4; ++f) {
        const int ra = (wm * 64 + f * 16 + q) * 72 + kk * 32 + g * 8;
        const int rb = (wn * 64 + f * 16 + q) * 72 + kk * 32 + g * 8;
        ah[f] = *(const bf16x8*)&lAh[ra];
        al[f] = *(const bf16x8*)&lAl[ra];
        bh[f] = *(const bf16x8*)&lBh[rb];
        bl[f] = *(const bf16x8*)&lBl[rb];
      }
      #pragma unroll
      for (int fm = 0; fm < 4; ++fm)
        #pragma unroll
        for (int fn = 0; fn < 4; ++fn) {
          acc[fm][fn] = MFMA16(ah[fm], bh[fn], acc[fm][fn]);
          acc[fm][fn] = MFMA16(ah[fm], bl[fn], acc[fm][fn]);
          acc[fm][fn] = MFMA16(al[fm], bh[fn], acc[fm][fn]);
        }
    }
  }

  // C/D layout: col = lane&15, row = (lane>>4)*4 + r   [m89-verified]
  #pragma unroll
  for (int fm = 0; fm < 4; ++fm)
    #pragma unroll
    for (int fn = 0; fn < 4; ++fn)
      #pragma unroll
      for (int r = 0; r < 4; ++r) {
        const size_t row = m0 + wm * 64 + fm * 16 + g * 4 + r;
        C[row * (size_t)N + n0 + wn * 64 + fn * 16 + q] = acc[fm][fn][r];
      }
}

// ---------------------------------------------------------------------------
// Gemma RMSNorm + RoPE, in place (fp32). Block 256 per (row, head).
// ---------------------------------------------------------------------------
__global__ __launch_bounds__(256) void norm_rope_naive(
    float* __restrict__ data, const float* __restrict__ w,
    const float* __restrict__ ropec, int hstride, int rowlen, int s_off)
{
  __shared__ float red[256];
  __shared__ float buf[256];
  const int t = threadIdx.x;
  const int m = blockIdx.x, h = blockIdx.y;

  float* p = data + (size_t)m * rowlen + h * hstride + t;
  const float x = *p;
  red[t] = x * x;
  __syncthreads();
  for (int s = 128; s > 0; s >>= 1) {
    if (t < s) red[t] += red[t + s];
    __syncthreads();
  }
  const float rr = rsqrtf(red[0] * (1.0f / 256.0f) + 1e-6f);
  float xn = x * rr * (1.0f + w[t]);
  buf[t] = xn;
  __syncthreads();
  if (t < 64) {
    const float part = buf[(t < 32) ? t + 32 : t - 32];
    const float sgn  = (t < 32) ? -1.0f : 1.0f;
    const float* rc = ropec + (size_t)(s_off + m) * 128;
    xn = xn * rc[t] + sgn * part * rc[64 + t];
  }
  *p = xn;
}

// ---------------------------------------------------------------------------
// MFMA flash attention (full, GQA rep=4) + sigmoid gate. fp32 I/O.
// 4 waves x 16 Q rows; KVBLK=32. Split-bf16 Q,K (QK^T) and V (PV); P plain.
// ---------------------------------------------------------------------------
__global__ __launch_bounds__(256) void attn_mfma(
    const float* __restrict__ qg, const float* __restrict__ kb,
    const float* __restrict__ vb, float* __restrict__ yb)
{
  __shared__ bf16 lKh[32 * 264], lKl[32 * 264];  // [kv][256+pad]
  __shared__ bf16 lVh[256 * 40], lVl[256 * 40];  // [d][kv pad 32->40]
  __shared__ bf16 lP[4 * 16 * 40];               // per-wave [q][kv pad]
  const int tid  = threadIdx.x;
  const int wave = tid >> 6, lane = tid & 63;
  const int g = lane >> 4, qc = lane & 15;
  const int h = blockIdx.y, q0 = blockIdx.x * 64, kvh = h >> 2;
  const int qrow = q0 + wave * 16 + qc;

  bf16x8 qh[8], ql[8];
  {
    const float* qp = qg + (size_t)qrow * 8192 + h * 512;
    #pragma unroll
    for (int kq = 0; kq < 8; ++kq) {
      float f[8];
      *(f32x4*)&f[0] = *(const f32x4*)&qp[kq * 32 + g * 8];
      *(f32x4*)&f[4] = *(const f32x4*)&qp[kq * 32 + g * 8 + 4];
      split8(f, qh[kq], ql[kq]);
    }
  }

  f32x4 o[16] = {};
  float mrow = -1e30f, lrow = 0.0f;
  const float scale = 0.0625f;      // 256^-0.5
  const float L2E = 1.44269504f;
  const float* kbase = kb + kvh * 256;
  const float* vbase = vb + kvh * 256;
  const int vp = (tid & 15) * 2, vc = (tid >> 4) * 16;
  bf16* const pl = lP + wave * (16 * 40);

  for (int t0 = 0; t0 < 2048; t0 += 32) {
    // ---- stage K (32x256) and V (2 rows x 16 cols / thread), fp32 regs ----
    float kf[4][8];
    #pragma unroll
    for (int i = 0; i < 4; ++i) {
      const int v = i * 256 + tid;
      const int row = v >> 5, c8 = (v & 31) << 3;
      const float* p = &kbase[(size_t)(t0 + row) * 1024 + c8];
      *(f32x4*)&kf[i][0] = *(const f32x4*)p;
      *(f32x4*)&kf[i][4] = *(const f32x4*)(p + 4);
    }
    float v0[16], v1[16];
    {
      const float* p0 = vbase + (size_t)(t0 + vp) * 1024 + vc;
      #pragma unroll
      for (int j = 0; j < 4; ++j) {
        *(f32x4*)&v0[j * 4] = *(const f32x4*)(p0 + j * 4);
        *(f32x4*)&v1[j * 4] = *(const f32x4*)(p0 + 1024 + j * 4);
      }
    }
    __syncthreads();                    // prev-tile LDS reads done
    #pragma unroll
    for (int i = 0; i < 4; ++i) {
      const int v = i * 256 + tid;
      const int row = v >> 5, c8 = (v & 31) << 3;
      bf16x8 hi, lo;
      split8(kf[i], hi, lo);
      *(bf16x8*)&lKh[row * 264 + c8] = hi;
      *(bf16x8*)&lKl[row * 264 + c8] = lo;
    }
    {
      unsigned* dh = (unsigned*)lVh;
      unsigned* dl = (unsigned*)lVl;
      #pragma unroll
      for (int j = 0; j < 16; ++j) {
        const bf16 h0 = (bf16)v0[j], h1 = (bf16)v1[j];
        const bf16 l0 = (bf16)(v0[j] - (float)h0);
        const bf16 l1 = (bf16)(v1[j] - (float)h1);
        const int off = (vc + j) * 20 + (vp >> 1);
        dh[off] = (unsigned)__builtin_bit_cast(unsigned short, h0) |
                  ((unsigned)__builtin_bit_cast(unsigned short, h1) << 16);
        dl[off] = (unsigned)__builtin_bit_cast(unsigned short, l0) |
                  ((unsigned)__builtin_bit_cast(unsigned short, l1) << 16);
      }
    }
    __syncthreads();

    // ---- S^T = K*Q^T (split): lane holds q=qc, kv rows half*16+g*4+r ----
    f32x4 st[2];
    #pragma unroll
    for (int half = 0; half < 2; ++half) {
      f32x4 s = {0.f, 0.f, 0.f, 0.f};
      #pragma unroll
      for (int kq = 0; kq < 8; ++kq) {
        const int ko = (half * 16 + qc) * 264 + kq * 32 + g * 8;
        const bf16x8 kh = *(const bf16x8*)&lKh[ko];
        const bf16x8 kl = *(const bf16x8*)&lKl[ko];
        s = MFMA16(kh, qh[kq], s);
        s = MFMA16(kh, ql[kq], s);
        s = MFMA16(kl, qh[kq], s);
      }
      st[half] = s;
    }

    // ---- online softmax (always rescale) ----
    float pm = st[0][0];
    #pragma unroll
    for (int r = 1; r < 4; ++r) pm = fmaxf(pm, st[0][r]);
    #pragma unroll
    for (int r = 0; r < 4; ++r) pm = fmaxf(pm, st[1][r]);
    pm *= scale;
    pm = fmaxf(pm, __shfl_xor(pm, 16, 64));
    pm = fmaxf(pm, __shfl_xor(pm, 32, 64));

    const float mnew = fmaxf(mrow, pm);
    const float corr = exp2f((mrow - mnew) * L2E);
    lrow *= corr;
    #pragma unroll
    for (int f = 0; f < 16; ++f) {
      o[f][0] *= corr; o[f][1] *= corr; o[f][2] *= corr; o[f][3] *= corr;
    }
    mrow = mnew;

    float ladd = 0.0f;
    #pragma unroll
    for (int half = 0; half < 2; ++half) {
      bf16x4 pk;
      #pragma unroll
      for (int r = 0; r < 4; ++r) {
        const float pv = exp2f((st[half][r] * scale - mrow) * L2E);
        ladd += pv;
        pk[r] = (bf16)pv;
      }
      *(bf16x4*)&pl[qc * 40 + half * 16 + g * 4] = pk;  // P[q][kv]
    }
    ladd += __shfl_xor(ladd, 16, 64);
    ladd += __shfl_xor(ladd, 32, 64);
    lrow += ladd;

    LDS_FENCE();   // P writes -> P read (same wave, cross-typed)

    // ---- O^T += (Vh + Vl) * P^T ----
    const bf16x8 pb = *(const bf16x8*)&pl[qc * 40 + g * 8];
    #pragma unroll
    for (int fm = 0; fm < 16; ++fm) {
      const int vo = (fm * 16 + qc) * 40 + g * 8;
      o[fm] = MFMA16(*(const bf16x8*)&lVh[vo], pb, o[fm]);
      o[fm] = MFMA16(*(const bf16x8*)&lVl[vo], pb, o[fm]);
    }
  }

  // ---- epilogue: y = (O/l) * sigmoid(gate) ----
  const float inv = 1.0f / lrow;
  const float* gp = qg + (size_t)qrow * 8192 + h * 512 + 256;
  float* yp = yb + (size_t)qrow * 4096 + h * 256;
  #pragma unroll
  for (int fm = 0; fm < 16; ++fm) {
    const int d0 = fm * 16 + g * 4;
    #pragma unroll
    for (int r = 0; r < 4; ++r) {
      const float gv = gp[d0 + r];
      const float sig = 1.0f / (1.0f + exp2f(-gv * L2E));
      yp[d0 + r] = o[fm][r] * inv * sig;
    }
  }
}

// ---------------------------------------------------------------------------
// Self-checks: sampled naive recompute vs device result.
// hdr bits: 1 = GEMM mismatch, 2 = attn mismatch, 4 = NaN in out.
// Sentinel: out[0] = 600 + 100*bits (700..1300) -> visible in absmax.
// ---------------------------------------------------------------------------
__global__ __launch_bounds__(256) void check_gemm(
    const float* __restrict__ A, const float* __restrict__ Bw,
    const float* __restrict__ C, int N, int K, unsigned MN,
    unsigned* __restrict__ hdr)
{
  const unsigned i = blockIdx.x * 256 + threadIdx.x;
  const unsigned idx = (unsigned)(((unsigned long long)i * 2654435761ull) % MN);
  const int m = (int)(idx / (unsigned)N), n = (int)(idx % (unsigned)N);
  float s = 0.0f;
  for (int k = 0; k < K; ++k) s += A[(size_t)m * K + k] * Bw[(size_t)n * K + k];
  if (fabsf(s - C[(size_t)m * N + n]) > 0.02f) atomicOr(hdr, 1u);
}

__global__ __launch_bounds__(256) void check_attn(
    const float* __restrict__ qg, const float* __restrict__ kb,
    const float* __restrict__ vb, const float* __restrict__ y,
    int CH, unsigned* __restrict__ hdr)
{
  __shared__ float qs[256];
  __shared__ float sc[2048];
  __shared__ float red[256];
  const int t = threadIdx.x;
  const int m = blockIdx.x * (CH >> 3) + (CH >> 4);
  const int h = blockIdx.y, kvh = h >> 2;

  const float* qrow = qg + (size_t)m * 8192 + h * 512;
  qs[t] = qrow[t];
  __syncthreads();
  for (int kk = 0; kk < 8; ++kk) {
    const int ki = kk * 256 + t;
    const float* krow = kb + (size_t)ki * 1024 + kvh * 256;
    float s = 0.0f;
    for (int d = 0; d < 256; ++d) s += qs[d] * krow[d];
    sc[ki] = s * 0.0625f;
  }
  __syncthreads();
  float lm = -1e30f;
  for (int kk = 0; kk < 8; ++kk) lm = fmaxf(lm, sc[kk * 256 + t]);
  red[t] = lm;
  __syncthreads();
  for (int s = 128; s > 0; s >>= 1) {
    if (t < s) red[t] = fmaxf(red[t], red[t + s]);
    __syncthreads();
  }
  const float mx = red[0];
  __syncthreads();
  float ls = 0.0f;
  for (int kk = 0; kk < 8; ++kk) {
    const int ki = kk * 256 + t;
    const float p = expf(sc[ki] - mx);
    sc[ki] = p;
    ls += p;
  }
  red[t] = ls;
  __syncthreads();
  for (int s = 128; s > 0; s >>= 1) {
    if (t < s) red[t] += red[t + s];
    __syncthreads();
  }
  const float inv = 1.0f / red[0];
  float o = 0.0f;
  const float* vcol = vb + kvh * 256 + t;
  for (int k = 0; k < 2048; ++k) o += sc[k] * vcol[(size_t)k * 1024];
  const float gate = qrow[256 + t];
  const float sig = 1.0f / (1.0f + expf(-gate));
  const float yref = o * inv * sig;
  const float yact = y[(size_t)m * 4096 + h * 256 + t];
  if (fabsf(yref - yact) > 0.03f) atomicOr(hdr, 2u);
}

__global__ __launch_bounds__(256) void scan_out_nan(
    const float* __restrict__ o, size_t n, unsigned* __restrict__ hdr)
{
  unsigned bad = 0;
  for (size_t i = (size_t)blockIdx.x * 256 + threadIdx.x; i < n;
       i += (size_t)gridDim.x * 256) {
    const float v = o[i];
    if (!(v == v)) bad = 1;
  }
  if (__any(bad) && (threadIdx.x & 63) == 0) atomicOr(hdr, 4u);
}

__global__ void encode_verdict(float* o, const unsigned* hdr) {
  if (threadIdx.x == 0 && hdr[0]) o[0] = 600.0f + 100.0f * (float)hdr[0];
}

// ---------------------------------------------------------------------------
extern "C" void kernel_launch(void* const* d_in, const int* in_sizes, int n_in,
                              void* d_out, int out_size, void* d_ws, size_t ws_size,
                              hipStream_t stream) {
  const float* x    = (const float*)d_in[0];
  const float* rope = (const float*)d_in[1];
  const float* wq   = (const float*)d_in[2];
  const float* wk   = (const float*)d_in[3];
  const float* wv   = (const float*)d_in[4];
  const float* wo   = (const float*)d_in[5];
  const float* qnw  = (const float*)d_in[6];
  const float* knw  = (const float*)d_in[7];
  float* out = (float*)d_out;

  if (out_size != 16777216) { write_val<<<1, 64, 0, stream>>>(out, 2000.0f); return; }
  const bool sizes_ok = (n_in == 8) &&
      in_sizes[0] == 16777216 && in_sizes[1] == 262144 &&
      in_sizes[2] == 33554432 && in_sizes[3] == 4194304 &&
      in_sizes[4] == 4194304  && in_sizes[5] == 16777216 &&
      in_sizes[6] == 256      && in_sizes[7] == 256;
  if (!sizes_ok) { write_val<<<1, 64, 0, stream>>>(out, 2500.0f); return; }

  // ws: [hdr 1KB | k 8.39MB | v 8.39MB | qg CH*32KB | y CH*16KB]
  const size_t KVB = 2048ull * 1024 * 4;
  const size_t fixed = 1024 + 2 * KVB;
  int CH = 2048;
  while (CH > 128 && fixed + (size_t)CH * 49152 > ws_size) CH >>= 1;
  if (fixed + (size_t)CH * 49152 > ws_size) {
    write_val<<<1, 64, 0, stream>>>(out, 3000.0f);
    return;
  }
  char* ws = (char*)d_ws;
  unsigned* hdr = (unsigned*)ws;
  float* kbb = (float*)(ws + 1024);
  float* vbb = (float*)(ws + 1024 + KVB);
  float* qgc = (float*)(ws + fixed);
  float* ycc = (float*)(ws + fixed + (size_t)CH * 32768);

  hipMemsetAsync(hdr, 0, 64, stream);

  for (int b = 0; b < 2; ++b) {
    const float* xb = x + (size_t)b * 2048 * 4096;
    gemm_bt_split<<<dim3(8, 16), 256, 0, stream>>>(xb, wk, kbb, 2048, 1024, 4096);
    if (b == 0)
      check_gemm<<<4, 256, 0, stream>>>(xb, wk, kbb, 1024, 4096, 2048u * 1024u, hdr);
    norm_rope_naive<<<dim3(2048, 4), 256, 0, stream>>>(kbb, knw, rope, 256, 1024, 0);
    gemm_bt_split<<<dim3(8, 16), 256, 0, stream>>>(xb, wv, vbb, 2048, 1024, 4096);
    for (int c = 0; c < 2048; c += CH) {
      gemm_bt_split<<<dim3(64, CH / 128), 256, 0, stream>>>(
          xb + (size_t)c * 4096, wq, qgc, CH, 8192, 4096);
      norm_rope_naive<<<dim3(CH, 16), 256, 0, stream>>>(qgc, qnw, rope, 512, 8192, c);
      attn_mfma<<<dim3(CH / 64, 16), 256, 0, stream>>>(qgc, kbb, vbb, ycc);
      if (b == 0 && c == 0)
        check_attn<<<dim3(8, 16), 256, 0, stream>>>(qgc, kbb, vbb, ycc, CH, hdr);
      gemm_bt_split<<<dim3(32, CH / 128), 256, 0, stream>>>(
          ycc, wo, out + ((size_t)b * 2048 + c) * 4096, CH, 4096, 4096);
    }
  }

  scan_out_nan<<<1024, 256, 0, stream>>>(out, (size_t)out_size, hdr);
  encode_verdict<<<1, 64, 0, stream>>>(out, hdr);
}

// Round 10
// 1995.667 us; speedup vs baseline: 24.1120x; 1.9750x over previous
//
#include <hip/hip_runtime.h>
#include <hip/hip_bf16.h>
#include <cstdint>
#include <cstddef>

typedef __bf16 bf16;
typedef __bf16 bf16x8 __attribute__((ext_vector_type(8)));
typedef __bf16 bf16x4 __attribute__((ext_vector_type(4)));
typedef float f32x4 __attribute__((ext_vector_type(4)));

#define MFMA16(a, b, c) __builtin_amdgcn_mfma_f32_16x16x32_bf16((a), (b), (c), 0, 0, 0)

// Order + drain LDS ops (TBAA can't see bf16x4-write vs bf16x8-read aliasing).
#define LDS_FENCE() do { \
    __builtin_amdgcn_sched_barrier(0); \
    asm volatile("s_waitcnt lgkmcnt(0)" ::: "memory"); \
    __builtin_amdgcn_sched_barrier(0); \
  } while (0)

__device__ __forceinline__ void split8(const float* f, bf16x8& hi, bf16x8& lo) {
  #pragma unroll
  for (int j = 0; j < 8; ++j) {
    const bf16 h = (bf16)f[j];
    hi[j] = h;
    lo[j] = (bf16)(f[j] - (float)h);
  }
}

__device__ __forceinline__ bf16x8 cvt8(const float* f) {
  bf16x8 h;
  #pragma unroll
  for (int j = 0; j < 8; ++j) h[j] = (bf16)f[j];
  return h;
}

__global__ void write_val(float* o, float v) {
  if (threadIdx.x == 0 && blockIdx.x == 0) o[0] = v;
}

// ---------------------------------------------------------------------------
// Elementwise fp32 -> (bf16 hi, bf16 lo) split pass. n8 = elems/8.
// ---------------------------------------------------------------------------
__global__ __launch_bounds__(256) void split_pass(
    const float* __restrict__ src, bf16* __restrict__ hi, bf16* __restrict__ lo,
    size_t n8)
{
  for (size_t i = (size_t)blockIdx.x * 256 + threadIdx.x; i < n8;
       i += (size_t)gridDim.x * 256) {
    float f[8];
    *(f32x4*)&f[0] = *(const f32x4*)&src[i * 8];
    *(f32x4*)&f[4] = *(const f32x4*)&src[i * 8 + 4];
    bf16x8 h, l;
    split8(f, h, l);
    *(bf16x8*)&hi[i * 8] = h;
    *(bf16x8*)&lo[i * 8] = l;
  }
}

// ---------------------------------------------------------------------------
// 3-term split GEMM, A pre-split: C = A(hi+lo) * B^T(fp32, split in-kernel).
// 128x128 tile, BK=64, 4 waves. Two B/C regions for fused launches:
// block n-panel < nsplit -> (B0,C0) else (B1,C1). ldc = region width.
// blockIdx.z: batch (A += z*aBatch elems, C += z*cBatch elems).
// ---------------------------------------------------------------------------
__global__ __launch_bounds__(256) void gemm3(
    const bf16* __restrict__ Ah, const bf16* __restrict__ Al,
    const float* __restrict__ B0, const float* __restrict__ B1, int nsplit,
    float* __restrict__ C0, float* __restrict__ C1,
    int K, size_t aBatch, size_t cBatch)
{
  __shared__ bf16 lAh[128 * 72], lAl[128 * 72];
  __shared__ bf16 lBh[128 * 72], lBl[128 * 72];
  const int tid  = threadIdx.x;
  const int wave = tid >> 6, lane = tid & 63;
  const int g = lane >> 4, q = lane & 15;
  const bool r0 = (int)blockIdx.x < nsplit;
  const float* Bw = r0 ? B0 : B1;
  float* C = (r0 ? C0 : C1) + blockIdx.z * cBatch;
  const int bn = r0 ? blockIdx.x : blockIdx.x - nsplit;
  const int ldc = (r0 ? nsplit : ((int)gridDim.x - nsplit)) * 128;
  const size_t n0 = (size_t)bn * 128;
  const size_t m0 = (size_t)blockIdx.y * 128;
  const bf16* Ahp = Ah + blockIdx.z * aBatch;
  const bf16* Alp = Al + blockIdx.z * aBatch;
  const int wm = wave >> 1, wn = wave & 1;
  const int sr = tid >> 3, sc8 = (tid & 7) << 3;

  f32x4 acc[4][4] = {};

  for (int k0 = 0; k0 < K; k0 += 64) {
    bf16x8 ah4[4], al4[4];
    float vb[4][8];
    #pragma unroll
    for (int i = 0; i < 4; ++i) {
      const int row = i * 32 + sr;
      ah4[i] = *(const bf16x8*)&Ahp[(m0 + row) * (size_t)K + k0 + sc8];
      al4[i] = *(const bf16x8*)&Alp[(m0 + row) * (size_t)K + k0 + sc8];
      const float* pb = &Bw[(n0 + row) * (size_t)K + k0 + sc8];
      *(f32x4*)&vb[i][0] = *(const f32x4*)pb;
      *(f32x4*)&vb[i][4] = *(const f32x4*)(pb + 4);
    }
    __syncthreads();                      // prev-tile LDS reads done
    #pragma unroll
    for (int i = 0; i < 4; ++i) {
      const int row = i * 32 + sr;
      *(bf16x8*)&lAh[row * 72 + sc8] = ah4[i];
      *(bf16x8*)&lAl[row * 72 + sc8] = al4[i];
      bf16x8 h, l;
      split8(vb[i], h, l);
      *(bf16x8*)&lBh[row * 72 + sc8] = h;
      *(bf16x8*)&lBl[row * 72 + sc8] = l;
    }
    __syncthreads();
    #pragma unroll
    for (int kk = 0; kk < 2; ++kk) {
      bf16x8 ah[4], al[4], bh[4], bl[4];
      #pragma unroll
      for (int f = 0; f < 4; ++f) {
        const int ra = (wm * 64 + f * 16 + q) * 72 + kk * 32 + g * 8;
        const int rb = (wn * 64 + f * 16 + q) * 72 + kk * 32 + g * 8;
        ah[f] = *(const bf16x8*)&lAh[ra];
        al[f] = *(const bf16x8*)&lAl[ra];
        bh[f] = *(const bf16x8*)&lBh[rb];
        bl[f] = *(const bf16x8*)&lBl[rb];
      }
      #pragma unroll
      for (int fm = 0; fm < 4; ++fm)
        #pragma unroll
        for (int fn = 0; fn < 4; ++fn) {
          acc[fm][fn] = MFMA16(ah[fm], bh[fn], acc[fm][fn]);
          acc[fm][fn] = MFMA16(ah[fm], bl[fn], acc[fm][fn]);
          acc[fm][fn] = MFMA16(al[fm], bh[fn], acc[fm][fn]);
        }
    }
  }

  // C/D layout: col = lane&15, row = (lane>>4)*4 + r
  #pragma unroll
  for (int fm = 0; fm < 4; ++fm)
    #pragma unroll
    for (int fn = 0; fn < 4; ++fn)
      #pragma unroll
      for (int r = 0; r < 4; ++r) {
        const size_t row = m0 + wm * 64 + fm * 16 + g * 4 + r;
        C[row * (size_t)ldc + n0 + wn * 64 + fn * 16 + q] = acc[fm][fn][r];
      }
}

// ---------------------------------------------------------------------------
// Gemma RMSNorm + RoPE, in place (fp32). Block 256 per (row, head).
// ---------------------------------------------------------------------------
__global__ __launch_bounds__(256) void norm_rope_naive(
    float* __restrict__ data, const float* __restrict__ w,
    const float* __restrict__ ropec, int hstride, int rowlen, int s_off)
{
  __shared__ float red[256];
  __shared__ float buf[256];
  const int t = threadIdx.x;
  const int m = blockIdx.x, h = blockIdx.y;
  const int s = (s_off + m) & 2047;       // position wraps per batch (S=2048)

  float* p = data + (size_t)m * rowlen + h * hstride + t;
  const float x = *p;
  red[t] = x * x;
  __syncthreads();
  for (int s2 = 128; s2 > 0; s2 >>= 1) {
    if (t < s2) red[t] += red[t + s2];
    __syncthreads();
  }
  const float rr = rsqrtf(red[0] * (1.0f / 256.0f) + 1e-6f);
  float xn = x * rr * (1.0f + w[t]);
  buf[t] = xn;
  __syncthreads();
  if (t < 64) {
    const float part = buf[(t < 32) ? t + 32 : t - 32];
    const float sgn  = (t < 32) ? -1.0f : 1.0f;
    const float* rc = ropec + (size_t)s * 128;
    xn = xn * rc[t] + sgn * part * rc[64 + t];
  }
  *p = xn;
}

// ---------------------------------------------------------------------------
// MFMA flash attention (GQA rep=4) + sigmoid gate. fp32 in, split-bf16 y out.
// Q,K plain bf16 (1-term QK); V 2-term; P bf16. 4 waves x 16 Q rows; KVBLK=32.
// ---------------------------------------------------------------------------
__global__ __launch_bounds__(256) void attn_mfma2(
    const float* __restrict__ qg, const float* __restrict__ kb,
    const float* __restrict__ vb, bf16* __restrict__ yh, bf16* __restrict__ yl)
{
  __shared__ bf16 lK[32 * 264];                  // [kv][256+pad]
  __shared__ bf16 lVh[256 * 40], lVl[256 * 40];  // [d][kv pad 32->40]
  __shared__ bf16 lP[4 * 16 * 40];               // per-wave [q][kv pad]
  const int tid  = threadIdx.x;
  const int wave = tid >> 6, lane = tid & 63;
  const int g = lane >> 4, qc = lane & 15;
  const int h = blockIdx.y, q0 = blockIdx.x * 64, kvh = h >> 2;
  const int qrow = q0 + wave * 16 + qc;

  bf16x8 qf[8];
  {
    const float* qp = qg + (size_t)qrow * 8192 + h * 512;
    #pragma unroll
    for (int kq = 0; kq < 8; ++kq) {
      float f[8];
      *(f32x4*)&f[0] = *(const f32x4*)&qp[kq * 32 + g * 8];
      *(f32x4*)&f[4] = *(const f32x4*)&qp[kq * 32 + g * 8 + 4];
      qf[kq] = cvt8(f);
    }
  }

  f32x4 o[16] = {};
  float mrow = -1e30f, lrow = 0.0f;
  const float scale = 0.0625f;      // 256^-0.5
  const float L2E = 1.44269504f;
  const float* kbase = kb + kvh * 256;
  const float* vbase = vb + kvh * 256;
  const int vp = (tid & 15) * 2, vc = (tid >> 4) * 16;
  bf16* const pl = lP + wave * (16 * 40);

  for (int t0 = 0; t0 < 2048; t0 += 32) {
    // ---- stage K (plain bf16) and V (2 rows x 16 cols, hi+lo) ----
    float kf[4][8];
    #pragma unroll
    for (int i = 0; i < 4; ++i) {
      const int v = i * 256 + tid;
      const int row = v >> 5, c8 = (v & 31) << 3;
      const float* p = &kbase[(size_t)(t0 + row) * 1024 + c8];
      *(f32x4*)&kf[i][0] = *(const f32x4*)p;
      *(f32x4*)&kf[i][4] = *(const f32x4*)(p + 4);
    }
    float v0[16], v1[16];
    {
      const float* p0 = vbase + (size_t)(t0 + vp) * 1024 + vc;
      #pragma unroll
      for (int j = 0; j < 4; ++j) {
        *(f32x4*)&v0[j * 4] = *(const f32x4*)(p0 + j * 4);
        *(f32x4*)&v1[j * 4] = *(const f32x4*)(p0 + 1024 + j * 4);
      }
    }
    __syncthreads();                    // prev-tile LDS reads done
    #pragma unroll
    for (int i = 0; i < 4; ++i) {
      const int v = i * 256 + tid;
      const int row = v >> 5, c8 = (v & 31) << 3;
      *(bf16x8*)&lK[row * 264 + c8] = cvt8(kf[i]);
    }
    {
      unsigned* dh = (unsigned*)lVh;
      unsigned* dl = (unsigned*)lVl;
      #pragma unroll
      for (int j = 0; j < 16; ++j) {
        const bf16 h0 = (bf16)v0[j], h1 = (bf16)v1[j];
        const bf16 l0 = (bf16)(v0[j] - (float)h0);
        const bf16 l1 = (bf16)(v1[j] - (float)h1);
        const int off = (vc + j) * 20 + (vp >> 1);
        dh[off] = (unsigned)__builtin_bit_cast(unsigned short, h0) |
                  ((unsigned)__builtin_bit_cast(unsigned short, h1) << 16);
        dl[off] = (unsigned)__builtin_bit_cast(unsigned short, l0) |
                  ((unsigned)__builtin_bit_cast(unsigned short, l1) << 16);
      }
    }
    __syncthreads();

    // ---- S^T = K*Q^T : lane holds q=qc, kv rows half*16+g*4+r ----
    f32x4 st[2];
    #pragma unroll
    for (int half = 0; half < 2; ++half) {
      f32x4 s = {0.f, 0.f, 0.f, 0.f};
      #pragma unroll
      for (int kq = 0; kq < 8; ++kq) {
        const bf16x8 ka = *(const bf16x8*)
            &lK[(half * 16 + qc) * 264 + kq * 32 + g * 8];
        s = MFMA16(ka, qf[kq], s);
      }
      st[half] = s;
    }

    // ---- online softmax (always rescale) ----
    float pm = st[0][0];
    #pragma unroll
    for (int r = 1; r < 4; ++r) pm = fmaxf(pm, st[0][r]);
    #pragma unroll
    for (int r = 0; r < 4; ++r) pm = fmaxf(pm, st[1][r]);
    pm *= scale;
    pm = fmaxf(pm, __shfl_xor(pm, 16, 64));
    pm = fmaxf(pm, __shfl_xor(pm, 32, 64));

    const float mnew = fmaxf(mrow, pm);
    const float corr = exp2f((mrow - mnew) * L2E);
    lrow *= corr;
    #pragma unroll
    for (int f = 0; f < 16; ++f) {
      o[f][0] *= corr; o[f][1] *= corr; o[f][2] *= corr; o[f][3] *= corr;
    }
    mrow = mnew;

    float ladd = 0.0f;
    #pragma unroll
    for (int half = 0; half < 2; ++half) {
      bf16x4 pk;
      #pragma unroll
      for (int r = 0; r < 4; ++r) {
        const float pv = exp2f((st[half][r] * scale - mrow) * L2E);
        ladd += pv;
        pk[r] = (bf16)pv;
      }
      *(bf16x4*)&pl[qc * 40 + half * 16 + g * 4] = pk;  // P[q][kv]
    }
    ladd += __shfl_xor(ladd, 16, 64);
    ladd += __shfl_xor(ladd, 32, 64);
    lrow += ladd;

    LDS_FENCE();   // P writes -> P read (same wave, cross-typed)

    // ---- O^T += (Vh + Vl) * P^T ----
    const bf16x8 pb = *(const bf16x8*)&pl[qc * 40 + g * 8];
    #pragma unroll
    for (int fm = 0; fm < 16; ++fm) {
      const int vo = (fm * 16 + qc) * 40 + g * 8;
      o[fm] = MFMA16(*(const bf16x8*)&lVh[vo], pb, o[fm]);
      o[fm] = MFMA16(*(const bf16x8*)&lVl[vo], pb, o[fm]);
    }
  }

  // ---- epilogue: y = (O/l)*sigmoid(gate), written pre-split (hi, lo) ----
  const float inv = 1.0f / lrow;
  const float* gp = qg + (size_t)qrow * 8192 + h * 512 + 256;
  bf16* yhp = yh + (size_t)qrow * 4096 + h * 256;
  bf16* ylp = yl + (size_t)qrow * 4096 + h * 256;
  #pragma unroll
  for (int fm = 0; fm < 16; ++fm) {
    const int d0 = fm * 16 + g * 4;
    bf16x4 hv, lv;
    #pragma unroll
    for (int r = 0; r < 4; ++r) {
      const float gv = gp[d0 + r];
      const float sig = 1.0f / (1.0f + exp2f(-gv * L2E));
      const float val = o[fm][r] * inv * sig;
      const bf16 hb = (bf16)val;
      hv[r] = hb;
      lv[r] = (bf16)(val - (float)hb);
    }
    *(bf16x4*)&yhp[d0] = hv;
    *(bf16x4*)&ylp[d0] = lv;
  }
}

// ---------------------------------------------------------------------------
extern "C" void kernel_launch(void* const* d_in, const int* in_sizes, int n_in,
                              void* d_out, int out_size, void* d_ws, size_t ws_size,
                              hipStream_t stream) {
  const float* x    = (const float*)d_in[0];
  const float* rope = (const float*)d_in[1];
  const float* wq   = (const float*)d_in[2];
  const float* wk   = (const float*)d_in[3];
  const float* wv   = (const float*)d_in[4];
  const float* wo   = (const float*)d_in[5];
  const float* qnw  = (const float*)d_in[6];
  const float* knw  = (const float*)d_in[7];
  float* out = (float*)d_out;

  if (out_size != 16777216) { write_val<<<1, 64, 0, stream>>>(out, 2000.0f); return; }
  const bool sizes_ok = (n_in == 8) &&
      in_sizes[0] == 16777216 && in_sizes[1] == 262144 &&
      in_sizes[2] == 33554432 && in_sizes[3] == 4194304 &&
      in_sizes[4] == 4194304  && in_sizes[5] == 16777216 &&
      in_sizes[6] == 256      && in_sizes[7] == 256;
  if (!sizes_ok) { write_val<<<1, 64, 0, stream>>>(out, 2500.0f); return; }

  // ws: [xh|xl (nb batches) | kbb|vbb fp32 (nb) | qgc fp32 CH | yh|yl CH]
  const size_t XS  = 2048ull * 4096;     // x elems per batch
  const size_t KVS = 2048ull * 1024;     // k/v elems per batch
  auto need = [&](int nb, int CHv) -> size_t {
    return (size_t)nb * XS * 4            // xh+xl (2B each)
         + (size_t)nb * KVS * 8           // kbb+vbb fp32
         + (size_t)CHv * 8192 * 4         // qgc fp32
         + (size_t)CHv * 4096 * 4;        // yh+yl (2B each)
  };
  int nb = 2, CH = 2048;
  while (CH > 128 && need(nb, CH) > ws_size) CH >>= 1;
  if (need(nb, CH) > ws_size) {
    nb = 1; CH = 2048;
    while (CH > 128 && need(nb, CH) > ws_size) CH >>= 1;
  }
  if (need(nb, CH) > ws_size) {
    write_val<<<1, 64, 0, stream>>>(out, 3000.0f);
    return;
  }

  char* ws = (char*)d_ws;
  bf16*  xh  = (bf16*)ws;
  bf16*  xl  = xh + (size_t)nb * XS;
  float* kbb = (float*)(xl + (size_t)nb * XS);
  float* vbb = kbb + (size_t)nb * KVS;
  float* qgc = vbb + (size_t)nb * KVS;
  bf16*  yh  = (bf16*)(qgc + (size_t)CH * 8192);
  bf16*  yl  = yh + (size_t)CH * 4096;

  if (nb == 2) {
    // split x (both batches), fused k+v GEMM for both batches, norm k
    split_pass<<<2048, 256, 0, stream>>>(x, xh, xl, 2 * XS / 8);
    gemm3<<<dim3(16, 16, 2), 256, 0, stream>>>(
        xh, xl, wk, wv, 8, kbb, vbb, 4096, XS, KVS);
    norm_rope_naive<<<dim3(4096, 4), 256, 0, stream>>>(kbb, knw, rope, 256, 1024, 0);
  }

  for (int b = 0; b < 2; ++b) {
    const int bi = (nb == 2) ? b : 0;     // buffer index
    if (nb == 1) {
      split_pass<<<2048, 256, 0, stream>>>(x + (size_t)b * XS, xh, xl, XS / 8);
      gemm3<<<dim3(16, 16, 1), 256, 0, stream>>>(
          xh, xl, wk, wv, 8, kbb, vbb, 4096, 0, 0);
      norm_rope_naive<<<dim3(2048, 4), 256, 0, stream>>>(kbb, knw, rope, 256, 1024, 0);
    }
    const bf16* xhb = xh + (size_t)bi * XS;
    const bf16* xlb = xl + (size_t)bi * XS;
    float* kbbb = kbb + (size_t)bi * KVS;
    float* vbbb = vbb + (size_t)bi * KVS;
    for (int c = 0; c < 2048; c += CH) {
      gemm3<<<dim3(64, CH / 128, 1), 256, 0, stream>>>(
          xhb + (size_t)c * 4096, xlb + (size_t)c * 4096,
          wq, wq, 64, qgc, qgc, 4096, 0, 0);
      norm_rope_naive<<<dim3(CH, 16), 256, 0, stream>>>(qgc, qnw, rope, 512, 8192, c);
      attn_mfma2<<<dim3(CH / 64, 16), 256, 0, stream>>>(qgc, kbbb, vbbb, yh, yl);
      gemm3<<<dim3(32, CH / 128, 1), 256, 0, stream>>>(
          yh, yl, wo, wo, 32,
          out + ((size_t)b * 2048 + c) * 4096, out + ((size_t)b * 2048 + c) * 4096,
          4096, 0, 0);
    }
  }
}

// Round 11
// 1062.488 us; speedup vs baseline: 45.2895x; 1.8783x over previous
//
#include <hip/hip_runtime.h>
#include <hip/hip_bf16.h>
#include <cstdint>
#include <cstddef>

typedef __bf16 bf16;
typedef __bf16 bf16x8 __attribute__((ext_vector_type(8)));
typedef __bf16 bf16x4 __attribute__((ext_vector_type(4)));
typedef float f32x4 __attribute__((ext_vector_type(4)));

#define MFMA16(a, b, c) __builtin_amdgcn_mfma_f32_16x16x32_bf16((a), (b), (c), 0, 0, 0)

// Order + drain LDS ops (TBAA can't see bf16x4-write vs bf16x8-read aliasing).
#define LDS_FENCE() do { \
    __builtin_amdgcn_sched_barrier(0); \
    asm volatile("s_waitcnt lgkmcnt(0)" ::: "memory"); \
    __builtin_amdgcn_sched_barrier(0); \
  } while (0)

__device__ __forceinline__ bf16x8 cvt8(const float* f) {
  bf16x8 h;
  #pragma unroll
  for (int j = 0; j < 8; ++j) h[j] = (bf16)f[j];
  return h;
}

// load 8 elems as bf16x8 (direct for bf16, convert for float)
__device__ __forceinline__ bf16x8 ldb8(const bf16* p) {
  return *(const bf16x8*)p;
}
__device__ __forceinline__ bf16x8 ldb8(const float* p) {
  float f[8];
  *(f32x4*)&f[0] = *(const f32x4*)p;
  *(f32x4*)&f[4] = *(const f32x4*)(p + 4);
  return cvt8(f);
}

__global__ void write_val(float* o, float v) {
  if (threadIdx.x == 0 && blockIdx.x == 0) o[0] = v;
}

// ---------------------------------------------------------------------------
// fp32 -> bf16 conversion pass. n8 = elems/8.
// ---------------------------------------------------------------------------
__global__ __launch_bounds__(256) void cvt_pass(
    const float* __restrict__ src, bf16* __restrict__ dst, size_t n8)
{
  for (size_t i = (size_t)blockIdx.x * 256 + threadIdx.x; i < n8;
       i += (size_t)gridDim.x * 256) {
    float f[8];
    *(f32x4*)&f[0] = *(const f32x4*)&src[i * 8];
    *(f32x4*)&f[4] = *(const f32x4*)&src[i * 8 + 4];
    *(bf16x8*)&dst[i * 8] = cvt8(f);
  }
}

// ---------------------------------------------------------------------------
// Plain bf16 MFMA GEMM: C[M,N] = A[M,K] * B[N,K]^T, fp32 accum, CT output.
// 128x128 tile, BK=64, 4 waves (2x2 of 64x64), reg-staged LDS stride 72.
// Two B/C regions (fused launches): block x < nsplit -> (B0,C0) else (B1,C1).
// blockIdx.z: batch offset on A (aBatch elems) and C (cBatch elems).
// ---------------------------------------------------------------------------
template <typename CT, typename BT>
__global__ __launch_bounds__(256) void gemm_bf(
    const bf16* __restrict__ A,
    const BT* __restrict__ B0, const BT* __restrict__ B1, int nsplit,
    CT* __restrict__ C0, CT* __restrict__ C1,
    int K, size_t aBatch, size_t cBatch)
{
  __shared__ bf16 lA[128 * 72];
  __shared__ bf16 lB[128 * 72];
  const int tid  = threadIdx.x;
  const int wave = tid >> 6, lane = tid & 63;
  const int g = lane >> 4, q = lane & 15;
  const bool r0 = (int)blockIdx.x < nsplit;
  const BT* Bw = r0 ? B0 : B1;
  CT* C = (r0 ? C0 : C1) + blockIdx.z * cBatch;
  const int bn = r0 ? blockIdx.x : blockIdx.x - nsplit;
  const int ldc = (r0 ? nsplit : ((int)gridDim.x - nsplit)) * 128;
  const size_t n0 = (size_t)bn * 128;
  const size_t m0 = (size_t)blockIdx.y * 128;
  const bf16* Ap = A + blockIdx.z * aBatch;
  const int wm = wave >> 1, wn = wave & 1;
  const int sr = tid >> 3, sc8 = (tid & 7) << 3;

  f32x4 acc[4][4] = {};

  for (int k0 = 0; k0 < K; k0 += 64) {
    bf16x8 sa[4], sb[4];
    #pragma unroll
    for (int i = 0; i < 4; ++i) {
      const int row = i * 32 + sr;
      sa[i] = ldb8(&Ap[(m0 + row) * (size_t)K + k0 + sc8]);
      sb[i] = ldb8(&Bw[(n0 + row) * (size_t)K + k0 + sc8]);
    }
    __syncthreads();                      // prev-tile LDS reads done
    #pragma unroll
    for (int i = 0; i < 4; ++i) {
      const int row = i * 32 + sr;
      *(bf16x8*)&lA[row * 72 + sc8] = sa[i];
      *(bf16x8*)&lB[row * 72 + sc8] = sb[i];
    }
    __syncthreads();
    #pragma unroll
    for (int kk = 0; kk < 2; ++kk) {
      bf16x8 af[4], bfr[4];
      #pragma unroll
      for (int f = 0; f < 4; ++f) {
        af[f]  = *(const bf16x8*)&lA[(wm * 64 + f * 16 + q) * 72 + kk * 32 + g * 8];
        bfr[f] = *(const bf16x8*)&lB[(wn * 64 + f * 16 + q) * 72 + kk * 32 + g * 8];
      }
      #pragma unroll
      for (int fm = 0; fm < 4; ++fm)
        #pragma unroll
        for (int fn = 0; fn < 4; ++fn)
          acc[fm][fn] = MFMA16(af[fm], bfr[fn], acc[fm][fn]);
    }
  }

  // C/D layout: col = lane&15, row = (lane>>4)*4 + r
  #pragma unroll
  for (int fm = 0; fm < 4; ++fm)
    #pragma unroll
    for (int fn = 0; fn < 4; ++fn)
      #pragma unroll
      for (int r = 0; r < 4; ++r) {
        const size_t row = m0 + wm * 64 + fm * 16 + g * 4 + r;
        C[row * (size_t)ldc + n0 + wn * 64 + fn * 16 + q] = (CT)acc[fm][fn][r];
      }
}

// ---------------------------------------------------------------------------
// Gemma RMSNorm + RoPE on bf16 data, in place. Block 256 per (row, head).
// ---------------------------------------------------------------------------
__global__ __launch_bounds__(256) void norm_rope_b(
    bf16* __restrict__ data, const float* __restrict__ w,
    const float* __restrict__ ropec, int hstride, int rowlen, int s_off)
{
  __shared__ float red[256];
  __shared__ float buf[256];
  const int t = threadIdx.x;
  const int m = blockIdx.x, h = blockIdx.y;
  const int s = (s_off + m) & 2047;       // position resets per batch (S=2048)

  bf16* p = data + (size_t)m * rowlen + h * hstride + t;
  const float x = (float)*p;
  red[t] = x * x;
  __syncthreads();
  for (int s2 = 128; s2 > 0; s2 >>= 1) {
    if (t < s2) red[t] += red[t + s2];
    __syncthreads();
  }
  const float rr = rsqrtf(red[0] * (1.0f / 256.0f) + 1e-6f);
  float xn = x * rr * (1.0f + w[t]);
  buf[t] = xn;
  __syncthreads();
  if (t < 64) {                           // RoPE dims 0..63; partner +-32
    const float part = buf[(t < 32) ? t + 32 : t - 32];
    const float sgn  = (t < 32) ? -1.0f : 1.0f;
    const float* rc = ropec + (size_t)s * 128;
    xn = xn * rc[t] + sgn * part * rc[64 + t];
  }
  *p = (bf16)xn;
}

// ---------------------------------------------------------------------------
// bf16 MFMA flash attention (GQA rep=4) + sigmoid gate. All-bf16 operands,
// fp32 softmax/accum. 4 waves x 16 Q rows; KVBLK=32.
// ---------------------------------------------------------------------------
__global__ __launch_bounds__(256) void attn_b(
    const bf16* __restrict__ qg, const bf16* __restrict__ kb,
    const bf16* __restrict__ vb, bf16* __restrict__ yb)
{
  __shared__ bf16 lK[32 * 264];    // [kv][256+pad]
  __shared__ bf16 lVt[256 * 40];   // [d][kv pad 32->40]
  __shared__ bf16 lP[4 * 16 * 40]; // per-wave [q][kv pad]
  const int tid  = threadIdx.x;
  const int wave = tid >> 6, lane = tid & 63;
  const int g = lane >> 4, qc = lane & 15;
  const int h = blockIdx.y, q0 = blockIdx.x * 64, kvh = h >> 2;
  const int qrow = q0 + wave * 16 + qc;

  bf16x8 qf[8];
  {
    const bf16* qp = qg + (size_t)qrow * 8192 + h * 512;
    #pragma unroll
    for (int kq = 0; kq < 8; ++kq)
      qf[kq] = *(const bf16x8*)&qp[kq * 32 + g * 8];
  }

  f32x4 o[16] = {};
  float mrow = -1e30f, lrow = 0.0f;
  const float scale = 0.0625f;      // 256^-0.5
  const float L2E = 1.44269504f;
  const bf16* kbase = kb + kvh * 256;
  const bf16* vbase = vb + kvh * 256;
  const int vp = (tid & 15) * 2, vc = (tid >> 4) * 16;
  bf16* const pl = lP + wave * (16 * 40);

  for (int t0 = 0; t0 < 2048; t0 += 32) {
    // ---- stage K rows and V^T (2 rows x 16 cols / thread) ----
    bf16x8 ks[4];
    #pragma unroll
    for (int i = 0; i < 4; ++i) {
      const int v = i * 256 + tid;
      const int row = v >> 5, c8 = (v & 31) << 3;
      ks[i] = *(const bf16x8*)&kbase[(size_t)(t0 + row) * 1024 + c8];
    }
    bf16x8 v0a, v0b, v1a, v1b;
    {
      const bf16* p0 = vbase + (size_t)(t0 + vp) * 1024 + vc;
      v0a = *(const bf16x8*)(p0);
      v0b = *(const bf16x8*)(p0 + 8);
      v1a = *(const bf16x8*)(p0 + 1024);
      v1b = *(const bf16x8*)(p0 + 1032);
    }
    __syncthreads();                    // prev-tile LDS reads done
    #pragma unroll
    for (int i = 0; i < 4; ++i) {
      const int v = i * 256 + tid;
      const int row = v >> 5, c8 = (v & 31) << 3;
      *(bf16x8*)&lK[row * 264 + c8] = ks[i];
    }
    {
      unsigned* dst = (unsigned*)lVt;
      #pragma unroll
      for (int j = 0; j < 8; ++j) {
        const int o0 = (vc + j) * 20 + (vp >> 1);
        const int o1 = (vc + 8 + j) * 20 + (vp >> 1);
        dst[o0] = (unsigned)__builtin_bit_cast(unsigned short, (bf16)v0a[j]) |
                  ((unsigned)__builtin_bit_cast(unsigned short, (bf16)v1a[j]) << 16);
        dst[o1] = (unsigned)__builtin_bit_cast(unsigned short, (bf16)v0b[j]) |
                  ((unsigned)__builtin_bit_cast(unsigned short, (bf16)v1b[j]) << 16);
      }
    }
    __syncthreads();

    // ---- S^T = K*Q^T : lane holds q=qc, kv rows half*16+g*4+r ----
    f32x4 st[2];
    #pragma unroll
    for (int half = 0; half < 2; ++half) {
      f32x4 s = {0.f, 0.f, 0.f, 0.f};
      #pragma unroll
      for (int kq = 0; kq < 8; ++kq) {
        const bf16x8 ka = *(const bf16x8*)
            &lK[(half * 16 + qc) * 264 + kq * 32 + g * 8];
        s = MFMA16(ka, qf[kq], s);
      }
      st[half] = s;
    }

    // ---- online softmax (always rescale) ----
    float pm = st[0][0];
    #pragma unroll
    for (int r = 1; r < 4; ++r) pm = fmaxf(pm, st[0][r]);
    #pragma unroll
    for (int r = 0; r < 4; ++r) pm = fmaxf(pm, st[1][r]);
    pm *= scale;
    pm = fmaxf(pm, __shfl_xor(pm, 16, 64));
    pm = fmaxf(pm, __shfl_xor(pm, 32, 64));

    const float mnew = fmaxf(mrow, pm);
    const float corr = exp2f((mrow - mnew) * L2E);
    lrow *= corr;
    #pragma unroll
    for (int f = 0; f < 16; ++f) {
      o[f][0] *= corr; o[f][1] *= corr; o[f][2] *= corr; o[f][3] *= corr;
    }
    mrow = mnew;

    float ladd = 0.0f;
    #pragma unroll
    for (int half = 0; half < 2; ++half) {
      bf16x4 pk;
      #pragma unroll
      for (int r = 0; r < 4; ++r) {
        const float pv = exp2f((st[half][r] * scale - mrow) * L2E);
        ladd += pv;
        pk[r] = (bf16)pv;
      }
      *(bf16x4*)&pl[qc * 40 + half * 16 + g * 4] = pk;  // P[q][kv]
    }
    ladd += __shfl_xor(ladd, 16, 64);
    ladd += __shfl_xor(ladd, 32, 64);
    lrow += ladd;

    LDS_FENCE();   // P writes -> P read (same wave, cross-typed)

    // ---- O^T += V^T * P^T ----
    const bf16x8 pb = *(const bf16x8*)&pl[qc * 40 + g * 8];
    #pragma unroll
    for (int fm = 0; fm < 16; ++fm) {
      const bf16x8 va = *(const bf16x8*)&lVt[(fm * 16 + qc) * 40 + g * 8];
      o[fm] = MFMA16(va, pb, o[fm]);
    }
  }

  // ---- epilogue: y = (O/l)*sigmoid(gate) -> bf16 ----
  const float inv = 1.0f / lrow;
  const bf16* gp = qg + (size_t)qrow * 8192 + h * 512 + 256;
  bf16* yp = yb + (size_t)qrow * 4096 + h * 256;
  #pragma unroll
  for (int fm = 0; fm < 16; ++fm) {
    const int d0 = fm * 16 + g * 4;
    bf16x4 ov;
    #pragma unroll
    for (int r = 0; r < 4; ++r) {
      const float gv = (float)gp[d0 + r];
      const float sig = 1.0f / (1.0f + exp2f(-gv * L2E));
      ov[r] = (bf16)(o[fm][r] * inv * sig);
    }
    *(bf16x4*)&yp[d0] = ov;
  }
}

// ---------------------------------------------------------------------------
extern "C" void kernel_launch(void* const* d_in, const int* in_sizes, int n_in,
                              void* d_out, int out_size, void* d_ws, size_t ws_size,
                              hipStream_t stream) {
  const float* x    = (const float*)d_in[0];
  const float* rope = (const float*)d_in[1];
  const float* wq   = (const float*)d_in[2];
  const float* wk   = (const float*)d_in[3];
  const float* wv   = (const float*)d_in[4];
  const float* wo   = (const float*)d_in[5];
  const float* qnw  = (const float*)d_in[6];
  const float* knw  = (const float*)d_in[7];
  float* out = (float*)d_out;

  if (out_size != 16777216) { write_val<<<1, 64, 0, stream>>>(out, 2000.0f); return; }
  const bool sizes_ok = (n_in == 8) &&
      in_sizes[0] == 16777216 && in_sizes[1] == 262144 &&
      in_sizes[2] == 33554432 && in_sizes[3] == 4194304 &&
      in_sizes[4] == 4194304  && in_sizes[5] == 16777216 &&
      in_sizes[6] == 256      && in_sizes[7] == 256;
  if (!sizes_ok) { write_val<<<1, 64, 0, stream>>>(out, 2500.0f); return; }

  const size_t XS  = 2048ull * 4096;     // x elems per batch
  const size_t KVS = 2048ull * 1024;     // k/v elems per batch
  const size_t WFIX = (33554432ull + 4194304 + 4194304 + 16777216) * 2; // 117.4MB
  auto needT = [&](bool w, int nb, int CHv) -> size_t {
    return (w ? WFIX : 0)
         + (size_t)nb * XS * 2            // x bf16
         + (size_t)nb * KVS * 2 * 2       // k,v bf16
         + (size_t)CHv * 8192 * 2         // qg chunk bf16
         + (size_t)CHv * 4096 * 2;        // y chunk bf16
  };
  bool useW = true; int nb = 2, CH = 2048;
  while (CH > 128 && needT(useW, nb, CH) > ws_size) CH >>= 1;
  if (needT(useW, nb, CH) > ws_size) {
    useW = false; CH = 2048;
    while (CH > 128 && needT(useW, nb, CH) > ws_size) CH >>= 1;
    if (needT(useW, nb, CH) > ws_size) {
      nb = 1; CH = 2048;
      while (CH > 128 && needT(useW, nb, CH) > ws_size) CH >>= 1;
    }
  }
  if (needT(useW, nb, CH) > ws_size) {
    write_val<<<1, 64, 0, stream>>>(out, 3000.0f);
    return;
  }

  char* ws = (char*)d_ws;
  bf16* wqb = nullptr; bf16* wkb = nullptr; bf16* wvb = nullptr; bf16* wob = nullptr;
  if (useW) {
    wqb = (bf16*)ws;               ws += 33554432ull * 2;
    wkb = (bf16*)ws;               ws += 4194304ull * 2;
    wvb = (bf16*)ws;               ws += 4194304ull * 2;
    wob = (bf16*)ws;               ws += 16777216ull * 2;
  }
  bf16* xb  = (bf16*)ws;           ws += (size_t)nb * XS * 2;
  bf16* kbb = (bf16*)ws;           ws += (size_t)nb * KVS * 2;
  bf16* vbb = (bf16*)ws;           ws += (size_t)nb * KVS * 2;
  bf16* qgc = (bf16*)ws;           ws += (size_t)CH * 8192 * 2;
  bf16* ycc = (bf16*)ws;

  if (useW) {
    cvt_pass<<<2048, 256, 0, stream>>>(wq, wqb, 33554432 / 8);
    cvt_pass<<<512,  256, 0, stream>>>(wk, wkb, 4194304 / 8);
    cvt_pass<<<512,  256, 0, stream>>>(wv, wvb, 4194304 / 8);
    cvt_pass<<<1024, 256, 0, stream>>>(wo, wob, 16777216 / 8);
  }

  if (nb == 2) {
    cvt_pass<<<2048, 256, 0, stream>>>(x, xb, 2 * XS / 8);
    if (useW)
      gemm_bf<bf16, bf16><<<dim3(16, 16, 2), 256, 0, stream>>>(
          xb, wkb, wvb, 8, kbb, vbb, 4096, XS, KVS);
    else
      gemm_bf<bf16, float><<<dim3(16, 16, 2), 256, 0, stream>>>(
          xb, wk, wv, 8, kbb, vbb, 4096, XS, KVS);
    norm_rope_b<<<dim3(4096, 4), 256, 0, stream>>>(kbb, knw, rope, 256, 1024, 0);
  }

  for (int b = 0; b < 2; ++b) {
    const int bi = (nb == 2) ? b : 0;
    if (nb == 1) {
      cvt_pass<<<2048, 256, 0, stream>>>(x + (size_t)b * XS, xb, XS / 8);
      if (useW)
        gemm_bf<bf16, bf16><<<dim3(16, 16, 1), 256, 0, stream>>>(
            xb, wkb, wvb, 8, kbb, vbb, 4096, 0, 0);
      else
        gemm_bf<bf16, float><<<dim3(16, 16, 1), 256, 0, stream>>>(
            xb, wk, wv, 8, kbb, vbb, 4096, 0, 0);
      norm_rope_b<<<dim3(2048, 4), 256, 0, stream>>>(kbb, knw, rope, 256, 1024, 0);
    }
    const bf16* xbb = xb + (size_t)bi * XS;
    bf16* kbbb = kbb + (size_t)bi * KVS;
    bf16* vbbb = vbb + (size_t)bi * KVS;
    for (int c = 0; c < 2048; c += CH) {
      if (useW)
        gemm_bf<bf16, bf16><<<dim3(64, CH / 128, 1), 256, 0, stream>>>(
            xbb + (size_t)c * 4096, wqb, wqb, 64, qgc, qgc, 4096, 0, 0);
      else
        gemm_bf<bf16, float><<<dim3(64, CH / 128, 1), 256, 0, stream>>>(
            xbb + (size_t)c * 4096, wq, wq, 64, qgc, qgc, 4096, 0, 0);
      norm_rope_b<<<dim3(CH, 16), 256, 0, stream>>>(qgc, qnw, rope, 512, 8192, c);
      attn_b<<<dim3(CH / 64, 16), 256, 0, stream>>>(qgc, kbbb, vbbb, ycc);
      float* outc = out + ((size_t)b * 2048 + c) * 4096;
      if (useW)
        gemm_bf<float, bf16><<<dim3(32, CH / 128, 1), 256, 0, stream>>>(
            ycc, wob, wob, 32, outc, outc, 4096, 0, 0);
      else
        gemm_bf<float, float><<<dim3(32, CH / 128, 1), 256, 0, stream>>>(
            ycc, wo, wo, 32, outc, outc, 4096, 0, 0);
    }
  }
}